// Round 1
// baseline (276.824 us; speedup 1.0000x reference)
//
#include <hip/hip_runtime.h>

// out[r,d] = ((x[r]*W[d] + b[d])*32 - mean_r) * rsqrt(var_r + 1e-5) * gamma[d] + beta[d]
// mean_r = 32*(x*mW + mB);  var_r = 1024*(x^2*varW + 2x*covWB + varB)

#define D_SIZE   1024
#define N_ROWS   65536          // BATCH(2048) * NUM_NODES(32)
#define SCALE_F  32.0f          // sqrt(1024)
#define LN_EPS_F 1e-5f

__global__ void stats_kernel(const float* __restrict__ W,
                             const float* __restrict__ bias,
                             float* __restrict__ stats) {
    // single wave of 64 lanes
    int lane = threadIdx.x;
    float sW = 0.f, sW2 = 0.f, sB = 0.f, sB2 = 0.f, sWB = 0.f;
    for (int i = lane; i < D_SIZE; i += 64) {
        float w = W[i];
        float b = bias[i];
        sW  += w;
        sW2 += w * w;
        sB  += b;
        sB2 += b * b;
        sWB += w * b;
    }
    #pragma unroll
    for (int off = 32; off > 0; off >>= 1) {
        sW  += __shfl_down(sW,  off);
        sW2 += __shfl_down(sW2, off);
        sB  += __shfl_down(sB,  off);
        sB2 += __shfl_down(sB2, off);
        sWB += __shfl_down(sWB, off);
    }
    if (lane == 0) {
        const float inv_d = 1.0f / (float)D_SIZE;
        float mW = sW * inv_d;
        float mB = sB * inv_d;
        stats[0] = mW;
        stats[1] = mB;
        stats[2] = sW2 * inv_d - mW * mW;   // varW (biased)
        stats[3] = sB2 * inv_d - mB * mB;   // varB (biased)
        stats[4] = sWB * inv_d - mW * mB;   // cov(W,b)
    }
}

__global__ __launch_bounds__(256, 8)
void fused_expand_ln_kernel(const float* __restrict__ x,
                            const float* __restrict__ W,
                            const float* __restrict__ bias,
                            const float* __restrict__ gamma,
                            const float* __restrict__ beta,
                            const float* __restrict__ stats,
                            float* __restrict__ out) {
    // Each block owns the full D range: thread t handles d = 4t .. 4t+3.
    // Per-thread W/b/gamma/beta live in registers across all rows.
    const float mW    = stats[0];
    const float mB    = stats[1];
    const float varW  = stats[2];
    const float varB  = stats[3];
    const float covWB = stats[4];

    const int d0 = threadIdx.x * 4;
    const float4 W4  = *reinterpret_cast<const float4*>(W     + d0);
    const float4 B4  = *reinterpret_cast<const float4*>(bias  + d0);
    const float4 G4  = *reinterpret_cast<const float4*>(gamma + d0);
    const float4 E4  = *reinterpret_cast<const float4*>(beta  + d0);

    for (int row = blockIdx.x; row < N_ROWS; row += gridDim.x) {
        const float xv   = x[row];                       // wave-uniform -> s_load
        const float mean = SCALE_F * (xv * mW + mB);
        const float var  = (SCALE_F * SCALE_F) *
                           (xv * xv * varW + 2.0f * xv * covWB + varB);
        const float inv  = rsqrtf(var + LN_EPS_F);

        float4 o;
        o.x = ((xv * W4.x + B4.x) * SCALE_F - mean) * inv * G4.x + E4.x;
        o.y = ((xv * W4.y + B4.y) * SCALE_F - mean) * inv * G4.y + E4.y;
        o.z = ((xv * W4.z + B4.z) * SCALE_F - mean) * inv * G4.z + E4.z;
        o.w = ((xv * W4.w + B4.w) * SCALE_F - mean) * inv * G4.w + E4.w;

        *reinterpret_cast<float4*>(out + (size_t)row * D_SIZE + d0) = o;
    }
}

extern "C" void kernel_launch(void* const* d_in, const int* in_sizes, int n_in,
                              void* d_out, int out_size, void* d_ws, size_t ws_size,
                              hipStream_t stream) {
    const float* x     = (const float*)d_in[0];   // (2048, 32)
    const float* W     = (const float*)d_in[1];   // (1024, 1)
    const float* bias  = (const float*)d_in[2];   // (1024,)
    const float* gamma = (const float*)d_in[3];   // (1024,)
    const float* beta  = (const float*)d_in[4];   // (1024,)
    float* out   = (float*)d_out;                 // (2048, 32, 1024) f32
    float* stats = (float*)d_ws;                  // 5 floats scratch

    stats_kernel<<<1, 64, 0, stream>>>(W, bias, stats);

    // memory-bound: ~2048 blocks, grid-stride over 65536 rows
    fused_expand_ln_kernel<<<2048, 256, 0, stream>>>(x, W, bias, gamma, beta,
                                                     stats, out);
}